// Round 14
// baseline (273.257 us; speedup 1.0000x reference)
//
#include <hip/hip_runtime.h>
#include <hip/hip_bf16.h>
#include <cstdint>

constexpr int BATCH = 4;
constexpr int CDIM  = 512;
constexpr int NHEAD = 8;
constexpr int HD    = 64;
constexpr int FSP   = 56;
constexpr int NTOK  = FSP * FSP;  // 3136
constexpr int KH    = 28;
constexpr int KNTOK = KH * KH;    // 784
constexpr float SCALE_ATT = 0.125f;
constexpr int BIAS_LD = 832;      // 13 chunks * 64, NATURAL k-order (R18), tail -3e4

typedef _Float16 f16;
typedef __attribute__((ext_vector_type(8))) _Float16 half8;
typedef __attribute__((ext_vector_type(4))) _Float16 half4;
typedef __attribute__((ext_vector_type(2))) _Float16 half2v;
typedef __attribute__((ext_vector_type(4))) float  floatx4;

// ---------------------------------------------------------------------------
// Mega-prep: one dispatch for all input reshapes.
//  - x / Wq / Wkv / Wp transposes (64x64 tiles, vectorized half8 stores)
//  - Wsr reorder
//  - bias table: ANALYTIC rel indices, F16, NATURAL k-order (R18).
// ---------------------------------------------------------------------------
__device__ __forceinline__ void tr64(const float* __restrict__ in,
                                     f16* __restrict__ out, int R, int C,
                                     int r0, int c0, float (*sm)[65], int tid) {
  const int rr = tid >> 2, cs = (tid & 3) * 16;
  const float* src = in + (size_t)(r0 + rr) * C + c0 + cs;
#pragma unroll
  for (int j = 0; j < 16; j += 4) *(float4*)&sm[rr][cs + j] = *(const float4*)&src[j];
  __syncthreads();
  f16* dh = out + (size_t)(c0 + rr) * R + r0 + cs;
  half8 v0, v1;
#pragma unroll
  for (int j = 0; j < 8; ++j) v0[j] = (f16)sm[cs + j][rr];
#pragma unroll
  for (int j = 0; j < 8; ++j) v1[j] = (f16)sm[cs + 8 + j][rr];
  *(half8*)&dh[0] = v0;
  *(half8*)&dh[8] = v1;
}

__global__ __launch_bounds__(256) void k_prep(const float* __restrict__ x,
                                              const float* __restrict__ Wq,
                                              const float* __restrict__ Wkv,
                                              const float* __restrict__ Wp,
                                              const float* __restrict__ Wsr,
                                              const float* __restrict__ pos,
                                              f16* __restrict__ xT,
                                              f16* __restrict__ WqT,
                                              f16* __restrict__ WkvT,
                                              f16* __restrict__ WpT,
                                              f16* __restrict__ WsrP,
                                              f16* __restrict__ biasT) {
  __shared__ float sm[64][65];
  const int tid = threadIdx.x;
  int bid = blockIdx.x;
  if (bid < 1568) {
    const int b = bid / 392, r = bid % 392;
    tr64(x + (size_t)b * CDIM * NTOK, xT + (size_t)b * NTOK * CDIM,
         CDIM, NTOK, (r % 8) * 64, (r / 8) * 64, sm, tid);
    return;
  }
  bid -= 1568;
  if (bid < 64)  { tr64(Wq,  WqT,  512, 512,  (bid % 8) * 64, (bid / 8) * 64, sm, tid); return; }
  bid -= 64;
  if (bid < 128) { tr64(Wkv, WkvT, 512, 1024, (bid % 8) * 64, (bid / 8) * 64, sm, tid); return; }
  bid -= 128;
  if (bid < 64)  { tr64(Wp,  WpT,  512, 512,  (bid % 8) * 64, (bid / 8) * 64, sm, tid); return; }
  bid -= 64;
  if (bid < 512) {
    const float* src = Wsr + (size_t)bid * 2048;
    f16* dh = WsrP + (size_t)bid * 2048;
    for (int kp = tid; kp < 2048; kp += 256) {
      const int dd = kp >> 9, c = kp & 511;
      dh[kp] = (f16)src[c * 4 + dd];
    }
    return;
  }
  bid -= 512;
  {
    const int n = bid;
    const int in_ = n / FSP, jn = n % FSP;
    const int cbase = 55 * 111 + 55 - in_ * 111 - jn;
    for (int i = tid; i < BIAS_LD; i += 256) {
      const int m = i;            // natural k-order (R18)
      float v = -30000.f;
      if (m < KNTOK) {
        const int im = m / FSP, jm = m % FSP;
        v = pos[cbase + im * 111 + jm];
      }
      biasT[(size_t)n * BIAS_LD + i] = (f16)v;
    }
  }
}

// ---------------------------------------------------------------------------
// MFMA GEMM core (R17, frozen): depth-2 pipeline with counted vmcnt, 3 LDS
// buffers (48 KB -> 3 blocks/CU), never vmcnt(0) in the main loop.
// ---------------------------------------------------------------------------
struct GemmSmem { f16 A[3][128 * 32]; f16 B[3][128 * 32]; };  // 24 KB + 24 KB

__device__ __forceinline__ void gl_lds(const f16* g, f16* l) {
  __builtin_amdgcn_global_load_lds(
      (const __attribute__((address_space(1))) void*)g,
      (__attribute__((address_space(3))) void*)l, 16, 0, 0);
}

__device__ __forceinline__ void gemm128(GemmSmem* sm,
    const f16* a0, const f16* a1, const f16* b0, const f16* b1,
    int lane, int wv, int wm, int wn, int quad, int tx,
    floatx4 acc[4][4]) {
  const int so = wv * 1024 + lane * 8;
  gl_lds(a0,      &sm->A[0][so]);
  gl_lds(a1,      &sm->A[0][so + 512]);
  gl_lds(b0,      &sm->B[0][so]);
  gl_lds(b1,      &sm->B[0][so + 512]);
  gl_lds(a0 + 32, &sm->A[1][so]);
  gl_lds(a1 + 32, &sm->A[1][so + 512]);
  gl_lds(b0 + 32, &sm->B[1][so]);
  gl_lds(b1 + 32, &sm->B[1][so + 512]);
  asm volatile("s_waitcnt vmcnt(4)" ::: "memory");   // tile 0 landed
  __builtin_amdgcn_s_barrier();
#pragma unroll
  for (int it = 0; it < 16; ++it) {
    const int cur = it % 3;
    if (it < 14) {
      const int pf = (it + 2) % 3;
      gl_lds(a0 + (it + 2) * 32, &sm->A[pf][so]);
      gl_lds(a1 + (it + 2) * 32, &sm->A[pf][so + 512]);
      gl_lds(b0 + (it + 2) * 32, &sm->B[pf][so]);
      gl_lds(b1 + (it + 2) * 32, &sm->B[pf][so + 512]);
    }
    half8 af[4], bf[4];
#pragma unroll
    for (int i = 0; i < 4; ++i)
      af[i] = *(const half8*)&sm->A[cur][(wm * 64 + i * 16 + tx) * 32 + quad * 8];
#pragma unroll
    for (int j = 0; j < 4; ++j)
      bf[j] = *(const half8*)&sm->B[cur][(wn * 64 + j * 16 + tx) * 32 + quad * 8];
#pragma unroll
    for (int j = 0; j < 4; ++j)
#pragma unroll
      for (int i = 0; i < 4; ++i)
        acc[i][j] = __builtin_amdgcn_mfma_f32_16x16x32_f16(af[i], bf[j], acc[i][j], 0, 0, 0);
    __builtin_amdgcn_sched_barrier(0);
    if (it < 14) asm volatile("s_waitcnt vmcnt(4)" ::: "memory");
    else         asm volatile("s_waitcnt vmcnt(0)" ::: "memory");
    __builtin_amdgcn_s_barrier();
  }
}

#define GEMM128_PRE()                                                     \
  const int tid = threadIdx.x, lane = tid & 63, wv = tid >> 6;            \
  const int wm = wv & 1, wn = wv >> 1, quad = lane >> 4, tx = lane & 15;  \
  const int lr = lane >> 2, lc = (lane & 3) * 8;                          \
  floatx4 acc[4][4];                                                      \
  _Pragma("unroll") for (int i = 0; i < 4; ++i)                           \
  _Pragma("unroll") for (int j = 0; j < 4; ++j)                           \
      acc[i][j] = (floatx4){0.f, 0.f, 0.f, 0.f};

// T1 XCD swizzle (R21, +5 µs): consecutive LOGICAL tiles (which share A/B
// panels) land on the SAME XCD's L2 instead of being round-robined across 8.
// Bijective because all three GEMM grids are divisible by 8.
#define XCD_SWZ(nwg) \
  const int bid = (blockIdx.x & 7) * ((nwg) >> 3) + (blockIdx.x >> 3);

// ---------------------------------------------------------------------------
// GEMM-A: Q projection (400 blocks) + SR-conv split-K (448 blocks) merged.
// ---------------------------------------------------------------------------
__global__ __launch_bounds__(256) void k_gemmA(const f16* __restrict__ xT,
                                               const f16* __restrict__ WqT,
                                               f16* __restrict__ Qh,
                                               const f16* __restrict__ WsrP,
                                               float* __restrict__ XRp) {
  __shared__ GemmSmem sm;
  GEMM128_PRE();
  XCD_SWZ(848);
  int wg = bid;
  if (wg < 400) {             // ---- Q projection: b4 x m25 x n4 ----
    const int b = wg / 100, t = wg % 100;
    const int m0 = (t >> 2) * 128, n0 = (t & 3) * 128;
    const f16* xb = xT + (size_t)b * NTOK * CDIM;
    const int r0 = wv * 32 + lr, r1 = r0 + 16;
    const f16* a0 = xb + (size_t)min(m0 + r0, NTOK - 1) * CDIM + lc;
    const f16* a1 = xb + (size_t)min(m0 + r1, NTOK - 1) * CDIM + lc;
    const f16* b0 = WqT + (size_t)(n0 + r0) * CDIM + lc;
    const f16* b1 = WqT + (size_t)(n0 + r1) * CDIM + lc;
    gemm128(&sm, a0, a1, b0, b1, lane, wv, wm, wn, quad, tx, acc);
    f16* qhB = Qh + (size_t)b * NTOK * CDIM;
#pragma unroll
    for (int i = 0; i < 4; ++i)
#pragma unroll
      for (int rg = 0; rg < 4; ++rg) {
        const int m = m0 + wm * 64 + i * 16 + quad * 4 + rg;
        if (m >= NTOK) continue;
#pragma unroll
        for (int j = 0; j < 4; ++j)
          qhB[(size_t)m * CDIM + n0 + wn * 64 + j * 16 + tx] = (f16)acc[i][j][rg];
      }
  } else {                    // ---- SR conv split-K: (b,kc)16 x m7 x n4 ----
    wg -= 400;
    const int bkc = wg / 28, r = wg % 28;
    const int b = bkc >> 2, kc = bkc & 3;
    const int m0 = (r >> 2) * 128, n0 = (r & 3) * 128;
    const f16* xb = xT + (size_t)b * NTOK * CDIM;
    const int r0 = wv * 32 + lr, r1 = r0 + 16;
    int am0 = m0 + r0; if (am0 >= KNTOK) am0 = 0;
    int am1 = m0 + r1; if (am1 >= KNTOK) am1 = 0;
    const int sp0 = 112 * (am0 / KH) + 2 * (am0 % KH) + (kc >> 1) * FSP + (kc & 1);
    const int sp1 = 112 * (am1 / KH) + 2 * (am1 % KH) + (kc >> 1) * FSP + (kc & 1);
    const f16* a0 = xb + (size_t)sp0 * CDIM + lc;
    const f16* a1 = xb + (size_t)sp1 * CDIM + lc;
    const f16* b0 = WsrP + (size_t)(n0 + r0) * 2048 + kc * 512 + lc;
    const f16* b1 = WsrP + (size_t)(n0 + r1) * 2048 + kc * 512 + lc;
    gemm128(&sm, a0, a1, b0, b1, lane, wv, wm, wn, quad, tx, acc);
    float* dst = XRp + (size_t)(kc * BATCH + b) * KNTOK * CDIM;
#pragma unroll
    for (int i = 0; i < 4; ++i)
#pragma unroll
      for (int rg = 0; rg < 4; ++rg) {
        const int m = m0 + wm * 64 + i * 16 + quad * 4 + rg;
        if (m >= KNTOK) continue;
#pragma unroll
        for (int j = 0; j < 4; ++j)
          dst[(size_t)m * CDIM + n0 + wn * 64 + j * 16 + tx] = acc[i][j][rg];
      }
  }
}

// ---------------------------------------------------------------------------
// LN (R18): wave-per-row.  784 blocks x 4 waves; each wave owns one row, lane
// covers 8 channels.  No LDS, no __syncthreads — full 64-lane shfl reduce.
// ---------------------------------------------------------------------------
__global__ __launch_bounds__(256) void k_ln(const float* __restrict__ XRp,
                                            const float* __restrict__ b_sr,
                                            const float* __restrict__ gamma,
                                            const float* __restrict__ beta,
                                            f16* __restrict__ oh) {
  const int tid = threadIdx.x, wv = tid >> 6, lane = tid & 63;
  const int row = blockIdx.x * 4 + wv;
  const size_t slab = (size_t)BATCH * KNTOK * CDIM;
  const float* p = XRp + (size_t)row * CDIM + lane * 8;
  float v[8];
#pragma unroll
  for (int j = 0; j < 8; j += 4) {
    float4 a0 = *(const float4*)&p[j];
    float4 a1 = *(const float4*)&p[j + slab];
    float4 a2 = *(const float4*)&p[j + 2 * slab];
    float4 a3 = *(const float4*)&p[j + 3 * slab];
    float4 bs = *(const float4*)&b_sr[lane * 8 + j];
    v[j]     = a0.x + a1.x + a2.x + a3.x + bs.x;
    v[j + 1] = a0.y + a1.y + a2.y + a3.y + bs.y;
    v[j + 2] = a0.z + a1.z + a2.z + a3.z + bs.z;
    v[j + 3] = a0.w + a1.w + a2.w + a3.w + bs.w;
  }
  float s = 0.f, s2 = 0.f;
#pragma unroll
  for (int j = 0; j < 8; ++j) { s += v[j]; s2 += v[j] * v[j]; }
#pragma unroll
  for (int mask = 32; mask >= 1; mask >>= 1) {
    s  += __shfl_xor(s, mask, 64);
    s2 += __shfl_xor(s2, mask, 64);
  }
  const float mu  = s * (1.f / CDIM);
  const float var = s2 * (1.f / CDIM) - mu * mu;
  const float rs  = rsqrtf(var + 1e-5f);
  half8 o;
#pragma unroll
  for (int j = 0; j < 8; ++j)
    o[j] = (f16)((v[j] - mu) * rs * gamma[lane * 8 + j] + beta[lane * 8 + j]);
  *(half8*)&oh[(size_t)row * CDIM + lane * 8] = o;
}

// ---------------------------------------------------------------------------
// KV projection (224 blocks) + scatter.  K -> [b][h][m][d]; V -> [b][h][d][m].
// ---------------------------------------------------------------------------
__global__ __launch_bounds__(256) void k_kvproj(const f16* __restrict__ XRh,
                                                const f16* __restrict__ WkvT,
                                                f16* __restrict__ Kh,
                                                f16* __restrict__ Vt) {
  __shared__ GemmSmem sm;
  GEMM128_PRE();
  XCD_SWZ(224);
  const int b = bid / 56, r = bid % 56;
  const int m0 = (r / 8) * 128, n0 = (r % 8) * 128;
  const f16* ab = XRh + (size_t)b * KNTOK * CDIM;
  const int r0 = wv * 32 + lr, r1 = r0 + 16;
  const f16* a0 = ab + (size_t)min(m0 + r0, KNTOK - 1) * CDIM + lc;
  const f16* a1 = ab + (size_t)min(m0 + r1, KNTOK - 1) * CDIM + lc;
  const f16* b0 = WkvT + (size_t)(n0 + r0) * CDIM + lc;
  const f16* b1 = WkvT + (size_t)(n0 + r1) * CDIM + lc;
  gemm128(&sm, a0, a1, b0, b1, lane, wv, wm, wn, quad, tx, acc);
#pragma unroll
  for (int i = 0; i < 4; ++i)
#pragma unroll
    for (int rg = 0; rg < 4; ++rg) {
      const int m = m0 + wm * 64 + i * 16 + quad * 4 + rg;
      if (m >= KNTOK) continue;
#pragma unroll
      for (int j = 0; j < 4; ++j) {
        const int o2 = n0 + wn * 64 + j * 16 + tx;
        const int d = o2 >> 4, hh = (o2 >> 1) & 7;
        const float v = acc[i][j][rg];
        if (o2 & 1)
          Vt[((size_t)(b * NHEAD + hh) * HD + d) * KNTOK + m] = (f16)v;
        else
          Kh[((size_t)(b * NHEAD + hh) * KNTOK + m) * HD + d] = (f16)v;
      }
    }
}

// ---------------------------------------------------------------------------
// Attention (R22 = R18 + T5 setprio around both MFMA clusters).  Regime: two
// independent blocks co-reside per CU at unsynchronized phases — setprio(1)
// biases the scheduler to keep the matrix pipe fed while the other block's
// waves do prefetch/exp VALU (m191 attn regime, not m190's lockstep null).
// Core structure frozen: swapped QK^T, packed-b32 P writes, aq hoisted from
// LDS Qhs, K/V dbuf + 1 barrier/chunk, f16 natural-order bias.
// ---------------------------------------------------------------------------
#define LSTR 72
__global__ __launch_bounds__(256) void k_attn(const f16* __restrict__ Qh,
                                              const f16* __restrict__ Kh,
                                              const f16* __restrict__ Vt,
                                              const f16* __restrict__ biasT,
                                              f16* __restrict__ Oh) {
  __shared__ f16 Qhs[128][LSTR];
  __shared__ f16 Khs[2][64][LSTR], Vts[2][64][LSTR];
  __shared__ f16 Ps[4][32][LSTR];
  const int b = blockIdx.x >> 3, h = blockIdx.x & 7;
  const int n0 = blockIdx.y * 128;
  const int tid = threadIdx.x, lane = tid & 63, wv = tid >> 6;
  const int quad = lane >> 4, tx = lane & 15;
  const int rr = tid >> 2, sg = (tid & 3) * 16;   // K/V staging coords
  const int qr = tid >> 1, qs = (tid & 1) * 32;   // Q staging coords

  const f16* khB = Kh + (size_t)(b * NHEAD + h) * KNTOK * HD;
  const f16* vtB = Vt + (size_t)(b * NHEAD + h) * HD * KNTOK;

  {  // stage Q (128 rows x 64, clamp tail rows) and chunk 0 of K/V -> buf 0
    const int qrow = min(n0 + qr, NTOK - 1);
    const f16* src = Qh + ((size_t)b * NTOK + qrow) * CDIM + h * HD + qs;
    *(half8*)&Qhs[qr][qs]      = *(const half8*)&src[0];
    *(half8*)&Qhs[qr][qs + 8]  = *(const half8*)&src[8];
    *(half8*)&Qhs[qr][qs + 16] = *(const half8*)&src[16];
    *(half8*)&Qhs[qr][qs + 24] = *(const half8*)&src[24];
    const size_t koff = (size_t)rr * HD + sg;
    *(half8*)&Khs[0][rr][sg]     = *(const half8*)&khB[koff];
    *(half8*)&Khs[0][rr][sg + 8] = *(const half8*)&khB[koff + 8];
    const size_t voff = (size_t)rr * KNTOK + sg;
    *(half8*)&Vts[0][rr][sg]     = *(const half8*)&vtB[voff];
    *(half8*)&Vts[0][rr][sg + 8] = *(const half8*)&vtB[voff + 8];
  }

  // bias base: row = q-row (i*16+tx), col base = quad*4 (k contiguous per rg)
  size_t bbase[2];
#pragma unroll
  for (int i = 0; i < 2; ++i) {
    const int grow = min(n0 + wv * 32 + i * 16 + tx, NTOK - 1);
    bbase[i] = (size_t)grow * BIAS_LD + quad * 4;
  }

  floatx4 acc_o[2][4];
#pragma unroll
  for (int i = 0; i < 2; ++i)
#pragma unroll
    for (int t = 0; t < 4; ++t) acc_o[i][t] = (floatx4){0.f, 0.f, 0.f, 0.f};
  float l_part[2] = {0.f, 0.f};
  __syncthreads();

  // hoisted Q fragments (loop-invariant): aq[i][ks]
  half8 aq[2][2];
#pragma unroll
  for (int i = 0; i < 2; ++i)
#pragma unroll
    for (int ks = 0; ks < 2; ++ks)
      aq[i][ks] = *(const half8*)&Qhs[wv * 32 + i * 16 + tx][ks * 32 + quad * 8];

  half8 nk0, nk1, nv0, nv1;
  for (int jc = 0; jc < 13; ++jc) {
    const int cur = jc & 1, nxt = cur ^ 1;
    if (jc < 12) {  // register prefetch of next K/V chunk
      const int mbn = (jc + 1) * 64;
      const int km = min(mbn + rr, KNTOK - 1);
      const size_t koff = (size_t)km * HD + sg;
      nk0 = *(const half8*)&khB[koff];
      nk1 = *(const half8*)&khB[koff + 8];
      const int vc = min(mbn + sg, KNTOK - 16);
      const size_t voff = (size_t)rr * KNTOK + vc;
      nv0 = *(const half8*)&vtB[voff];
      nv1 = *(const half8*)&vtB[voff + 8];
    }

    // ---- S^T = K Q^T : sc[i][t][rg] = S[k = t*16+quad*4+rg][q = i*16+tx] ----
    floatx4 sc[2][4];
#pragma unroll
    for (int i = 0; i < 2; ++i)
#pragma unroll
      for (int t = 0; t < 4; ++t) sc[i][t] = (floatx4){0.f, 0.f, 0.f, 0.f};
    __builtin_amdgcn_s_setprio(1);
#pragma unroll
    for (int ks = 0; ks < 2; ++ks) {
      const int kk = ks * 32 + quad * 8;
#pragma unroll
      for (int t = 0; t < 4; ++t) {
        const half8 bk = *(const half8*)&Khs[cur][t * 16 + tx][kk];
#pragma unroll
        for (int i = 0; i < 2; ++i)
          sc[i][t] = __builtin_amdgcn_mfma_f32_16x16x32_f16(bk, aq[i][ks], sc[i][t], 0, 0, 0);
      }
    }
    __builtin_amdgcn_s_setprio(0);

    // ---- softmax: P[q][k] with k-runs of 4 per lane -> packed b32 writes ----
#pragma unroll
    for (int i = 0; i < 2; ++i) {
      const int prow = i * 16 + tx;
#pragma unroll
      for (int t = 0; t < 4; ++t) {
        const half4 bb = *(const half4*)&biasT[bbase[i] + jc * 64 + t * 16];
        const float p0 = __expf(fmaf(sc[i][t][0], SCALE_ATT, (float)bb[0]));
        const float p1 = __expf(fmaf(sc[i][t][1], SCALE_ATT, (float)bb[1]));
        const float p2 = __expf(fmaf(sc[i][t][2], SCALE_ATT, (float)bb[2]));
        const float p3 = __expf(fmaf(sc[i][t][3], SCALE_ATT, (float)bb[3]));
        l_part[i] += (p0 + p1) + (p2 + p3);
        half2v h01 = {(f16)p0, (f16)p1};
        half2v h23 = {(f16)p2, (f16)p3};
        *(half2v*)&Ps[wv][prow][t * 16 + quad * 4]     = h01;
        *(half2v*)&Ps[wv][prow][t * 16 + quad * 4 + 2] = h23;
      }
    }

    // ---- O += P V ----
    __builtin_amdgcn_s_setprio(1);
#pragma unroll
    for (int ks = 0; ks < 2; ++ks) {
      const int kk = ks * 32 + quad * 8;
      half8 ap[2];
#pragma unroll
      for (int i = 0; i < 2; ++i)
        ap[i] = *(const half8*)&Ps[wv][i * 16 + tx][kk];
#pragma unroll
      for (int t = 0; t < 4; ++t) {
        const half8 bv = *(const half8*)&Vts[cur][t * 16 + tx][kk];
#pragma unroll
        for (int i = 0; i < 2; ++i)
          acc_o[i][t] = __builtin_amdgcn_mfma_f32_16x16x32_f16(ap[i], bv, acc_o[i][t], 0, 0, 0);
      }
    }
    __builtin_amdgcn_s_setprio(0);
    if (jc < 12) {  // write prefetched chunk into the other buffer (no hazard)
      *(half8*)&Khs[nxt][rr][sg]     = nk0;
      *(half8*)&Khs[nxt][rr][sg + 8] = nk1;
      *(half8*)&Vts[nxt][rr][sg]     = nv0;
      *(half8*)&Vts[nxt][rr][sg + 8] = nv1;
    }
    __syncthreads();   // single barrier: next-buf writes visible, cur reads done
  }

  // ---- epilogue: row-sum lives per (i, tx); reduce over quads, then
  //      redistribute to the acc layout (row = i*16 + quad*4 + rg). ----
#pragma unroll
  for (int i = 0; i < 2; ++i) {
    float l = l_part[i];
    l += __shfl_xor(l, 16, 64);
    l += __shfl_xor(l, 32, 64);   // all lanes now hold sum for row i*16+tx
#pragma unroll
    for (int rg = 0; rg < 4; ++rg) {
      const float inv = 1.f / __shfl(l, quad * 4 + rg, 64);
      const int grow = n0 + wv * 32 + i * 16 + quad * 4 + rg;
      if (grow < NTOK) {
        const size_t base = ((size_t)b * NTOK + grow) * CDIM + h * HD;
#pragma unroll
        for (int t = 0; t < 4; ++t)
          Oh[base + t * 16 + tx] = (f16)(acc_o[i][t][rg] * inv);
      }
    }
  }
}

// ---------------------------------------------------------------------------
// Output projection (400 blocks, 128x128) + bp, fp32 transposed (b, co, n).
// ---------------------------------------------------------------------------
__global__ __launch_bounds__(256) void k_outproj(const f16* __restrict__ Og,
                                                 const f16* __restrict__ WpT,
                                                 const float* __restrict__ bp,
                                                 float* __restrict__ out) {
  __shared__ GemmSmem sm;
  GEMM128_PRE();
  XCD_SWZ(400);
  const int b = bid / 100, t = bid % 100;
  const int m0 = (t >> 2) * 128, n0 = (t & 3) * 128;
  const f16* ab = Og + (size_t)b * NTOK * CDIM;
  const int r0 = wv * 32 + lr, r1 = r0 + 16;
  const f16* a0 = ab + (size_t)min(m0 + r0, NTOK - 1) * CDIM + lc;
  const f16* a1 = ab + (size_t)min(m0 + r1, NTOK - 1) * CDIM + lc;
  const f16* b0 = WpT + (size_t)(n0 + r0) * CDIM + lc;
  const f16* b1 = WpT + (size_t)(n0 + r1) * CDIM + lc;
  gemm128(&sm, a0, a1, b0, b1, lane, wv, wm, wn, quad, tx, acc);
#pragma unroll
  for (int j = 0; j < 4; ++j) {
    const int co = n0 + wn * 64 + j * 16 + tx;
    const float bpv = bp[co];
    float* obase = out + ((size_t)b * CDIM + co) * NTOK;
#pragma unroll
    for (int i = 0; i < 4; ++i) {
      const int mb4 = m0 + wm * 64 + i * 16 + quad * 4;
      if (mb4 < NTOK) {
        floatx4 v = acc[i][j] + bpv;
        *(floatx4*)&obase[mb4] = v;
      }
    }
  }
}

// ---------------------------------------------------------------------------
extern "C" void kernel_launch(void* const* d_in, const int* in_sizes, int n_in,
                              void* d_out, int out_size, void* d_ws, size_t ws_size,
                              hipStream_t stream) {
  const float* x     = (const float*)d_in[0];
  const float* Wq    = (const float*)d_in[1];
  const float* Wkv   = (const float*)d_in[2];
  const float* Wsr   = (const float*)d_in[3];
  const float* b_sr  = (const float*)d_in[4];
  const float* gamma = (const float*)d_in[5];
  const float* beta  = (const float*)d_in[6];
  const float* Wp    = (const float*)d_in[7];
  const float* bp    = (const float*)d_in[8];
  const float* pos   = (const float*)d_in[9];
  float* out = (float*)d_out;

  char* p = (char*)d_ws;
  auto alloc = [&](size_t bytes) -> void* {
    void* r = (void*)p;
    p += (bytes + 255) & ~(size_t)255;
    return r;
  };
  const size_t SZ_BNC = (size_t)BATCH * NTOK * CDIM;
  const size_t SZ_BKC = (size_t)BATCH * KNTOK * CDIM;
  const size_t SZ_KV  = (size_t)BATCH * NHEAD * KNTOK * HD;

  f16* xT    = (f16*)alloc(SZ_BNC * 2);          // aliased later as Og
  f16* WqT   = (f16*)alloc(512 * 512 * 2);
  f16* WkvT  = (f16*)alloc(1024 * 512 * 2);
  f16* WpT   = (f16*)alloc(512 * 512 * 2);
  f16* WsrP  = (f16*)alloc(512 * 2048 * 2);
  f16* Qh    = (f16*)alloc(SZ_BNC * 2);
  float* XRp = (float*)alloc(SZ_BKC * 4 * 4);    // 4 split-K partials; aliased: Kh
  f16* XRh   = (f16*)alloc(SZ_BKC * 2);
  f16* Vt    = (f16*)alloc(SZ_KV * 2);
  f16* biasT = (f16*)alloc((size_t)NTOK * BIAS_LD * 2);   // f16 table, natural order

  f16* Kh = (f16*)XRp;  // XRp dead after k_ln; Kh written by k_kvproj
  f16* Og = xT;         // xT dead after k_gemmA

  const dim3 blk(256);
  k_prep   <<<dim3(5472), blk, 0, stream>>>(x, Wq, Wkv, Wp, Wsr, pos,
                                            xT, WqT, WkvT, WpT, WsrP, biasT);
  k_gemmA  <<<dim3(848),  blk, 0, stream>>>(xT, WqT, Qh, WsrP, XRp);
  k_ln     <<<dim3(BATCH * KNTOK / 4), blk, 0, stream>>>(XRp, b_sr, gamma, beta, XRh);
  k_kvproj <<<dim3(224),  blk, 0, stream>>>(XRh, WkvT, Kh, Vt);
  k_attn   <<<dim3(BATCH * NHEAD, 25), blk, 0, stream>>>(Qh, Kh, Vt, biasT, Og);
  k_outproj<<<dim3(400),  blk, 0, stream>>>(Og, WpT, bp, out);
}

// Round 15
// 266.939 us; speedup vs baseline: 1.0237x; 1.0237x over previous
//
#include <hip/hip_runtime.h>
#include <hip/hip_bf16.h>
#include <cstdint>

constexpr int BATCH = 4;
constexpr int CDIM  = 512;
constexpr int NHEAD = 8;
constexpr int HD    = 64;
constexpr int FSP   = 56;
constexpr int NTOK  = FSP * FSP;  // 3136
constexpr int KH    = 28;
constexpr int KNTOK = KH * KH;    // 784
constexpr float SCALE_ATT = 0.125f;
constexpr int BIAS_LD = 832;      // 13 chunks * 64, NATURAL k-order (R18), tail -3e4

typedef _Float16 f16;
typedef __attribute__((ext_vector_type(8))) _Float16 half8;
typedef __attribute__((ext_vector_type(4))) _Float16 half4;
typedef __attribute__((ext_vector_type(2))) _Float16 half2v;
typedef __attribute__((ext_vector_type(4))) float  floatx4;

// ---------------------------------------------------------------------------
// Mega-prep: one dispatch for all input reshapes.
//  - x / Wq / Wkv / Wp transposes (64x64 tiles, vectorized half8 stores)
//  - Wsr reorder
//  - bias table: ANALYTIC rel indices, F16, NATURAL k-order (R18).
// ---------------------------------------------------------------------------
__device__ __forceinline__ void tr64(const float* __restrict__ in,
                                     f16* __restrict__ out, int R, int C,
                                     int r0, int c0, float (*sm)[65], int tid) {
  const int rr = tid >> 2, cs = (tid & 3) * 16;
  const float* src = in + (size_t)(r0 + rr) * C + c0 + cs;
#pragma unroll
  for (int j = 0; j < 16; j += 4) *(float4*)&sm[rr][cs + j] = *(const float4*)&src[j];
  __syncthreads();
  f16* dh = out + (size_t)(c0 + rr) * R + r0 + cs;
  half8 v0, v1;
#pragma unroll
  for (int j = 0; j < 8; ++j) v0[j] = (f16)sm[cs + j][rr];
#pragma unroll
  for (int j = 0; j < 8; ++j) v1[j] = (f16)sm[cs + 8 + j][rr];
  *(half8*)&dh[0] = v0;
  *(half8*)&dh[8] = v1;
}

__global__ __launch_bounds__(256) void k_prep(const float* __restrict__ x,
                                              const float* __restrict__ Wq,
                                              const float* __restrict__ Wkv,
                                              const float* __restrict__ Wp,
                                              const float* __restrict__ Wsr,
                                              const float* __restrict__ pos,
                                              f16* __restrict__ xT,
                                              f16* __restrict__ WqT,
                                              f16* __restrict__ WkvT,
                                              f16* __restrict__ WpT,
                                              f16* __restrict__ WsrP,
                                              f16* __restrict__ biasT) {
  __shared__ float sm[64][65];
  const int tid = threadIdx.x;
  int bid = blockIdx.x;
  if (bid < 1568) {
    const int b = bid / 392, r = bid % 392;
    tr64(x + (size_t)b * CDIM * NTOK, xT + (size_t)b * NTOK * CDIM,
         CDIM, NTOK, (r % 8) * 64, (r / 8) * 64, sm, tid);
    return;
  }
  bid -= 1568;
  if (bid < 64)  { tr64(Wq,  WqT,  512, 512,  (bid % 8) * 64, (bid / 8) * 64, sm, tid); return; }
  bid -= 64;
  if (bid < 128) { tr64(Wkv, WkvT, 512, 1024, (bid % 8) * 64, (bid / 8) * 64, sm, tid); return; }
  bid -= 128;
  if (bid < 64)  { tr64(Wp,  WpT,  512, 512,  (bid % 8) * 64, (bid / 8) * 64, sm, tid); return; }
  bid -= 64;
  if (bid < 512) {
    const float* src = Wsr + (size_t)bid * 2048;
    f16* dh = WsrP + (size_t)bid * 2048;
    for (int kp = tid; kp < 2048; kp += 256) {
      const int dd = kp >> 9, c = kp & 511;
      dh[kp] = (f16)src[c * 4 + dd];
    }
    return;
  }
  bid -= 512;
  {
    const int n = bid;
    const int in_ = n / FSP, jn = n % FSP;
    const int cbase = 55 * 111 + 55 - in_ * 111 - jn;
    for (int i = tid; i < BIAS_LD; i += 256) {
      const int m = i;            // natural k-order (R18)
      float v = -30000.f;
      if (m < KNTOK) {
        const int im = m / FSP, jm = m % FSP;
        v = pos[cbase + im * 111 + jm];
      }
      biasT[(size_t)n * BIAS_LD + i] = (f16)v;
    }
  }
}

// ---------------------------------------------------------------------------
// MFMA GEMM core (R17, frozen): depth-2 pipeline with counted vmcnt, 3 LDS
// buffers (48 KB -> 3 blocks/CU), never vmcnt(0) in the main loop.
// ---------------------------------------------------------------------------
struct GemmSmem { f16 A[3][128 * 32]; f16 B[3][128 * 32]; };  // 24 KB + 24 KB

__device__ __forceinline__ void gl_lds(const f16* g, f16* l) {
  __builtin_amdgcn_global_load_lds(
      (const __attribute__((address_space(1))) void*)g,
      (__attribute__((address_space(3))) void*)l, 16, 0, 0);
}

__device__ __forceinline__ void gemm128(GemmSmem* sm,
    const f16* a0, const f16* a1, const f16* b0, const f16* b1,
    int lane, int wv, int wm, int wn, int quad, int tx,
    floatx4 acc[4][4]) {
  const int so = wv * 1024 + lane * 8;
  gl_lds(a0,      &sm->A[0][so]);
  gl_lds(a1,      &sm->A[0][so + 512]);
  gl_lds(b0,      &sm->B[0][so]);
  gl_lds(b1,      &sm->B[0][so + 512]);
  gl_lds(a0 + 32, &sm->A[1][so]);
  gl_lds(a1 + 32, &sm->A[1][so + 512]);
  gl_lds(b0 + 32, &sm->B[1][so]);
  gl_lds(b1 + 32, &sm->B[1][so + 512]);
  asm volatile("s_waitcnt vmcnt(4)" ::: "memory");   // tile 0 landed
  __builtin_amdgcn_s_barrier();
#pragma unroll
  for (int it = 0; it < 16; ++it) {
    const int cur = it % 3;
    if (it < 14) {
      const int pf = (it + 2) % 3;
      gl_lds(a0 + (it + 2) * 32, &sm->A[pf][so]);
      gl_lds(a1 + (it + 2) * 32, &sm->A[pf][so + 512]);
      gl_lds(b0 + (it + 2) * 32, &sm->B[pf][so]);
      gl_lds(b1 + (it + 2) * 32, &sm->B[pf][so + 512]);
    }
    half8 af[4], bf[4];
#pragma unroll
    for (int i = 0; i < 4; ++i)
      af[i] = *(const half8*)&sm->A[cur][(wm * 64 + i * 16 + tx) * 32 + quad * 8];
#pragma unroll
    for (int j = 0; j < 4; ++j)
      bf[j] = *(const half8*)&sm->B[cur][(wn * 64 + j * 16 + tx) * 32 + quad * 8];
#pragma unroll
    for (int j = 0; j < 4; ++j)
#pragma unroll
      for (int i = 0; i < 4; ++i)
        acc[i][j] = __builtin_amdgcn_mfma_f32_16x16x32_f16(af[i], bf[j], acc[i][j], 0, 0, 0);
    __builtin_amdgcn_sched_barrier(0);
    if (it < 14) asm volatile("s_waitcnt vmcnt(4)" ::: "memory");
    else         asm volatile("s_waitcnt vmcnt(0)" ::: "memory");
    __builtin_amdgcn_s_barrier();
  }
}

#define GEMM128_PRE()                                                     \
  const int tid = threadIdx.x, lane = tid & 63, wv = tid >> 6;            \
  const int wm = wv & 1, wn = wv >> 1, quad = lane >> 4, tx = lane & 15;  \
  const int lr = lane >> 2, lc = (lane & 3) * 8;                          \
  floatx4 acc[4][4];                                                      \
  _Pragma("unroll") for (int i = 0; i < 4; ++i)                           \
  _Pragma("unroll") for (int j = 0; j < 4; ++j)                           \
      acc[i][j] = (floatx4){0.f, 0.f, 0.f, 0.f};

// T1 XCD swizzle (R21, +5 µs): consecutive LOGICAL tiles (which share A/B
// panels) land on the SAME XCD's L2 instead of being round-robined across 8.
// Bijective because all three GEMM grids are divisible by 8.
#define XCD_SWZ(nwg) \
  const int bid = (blockIdx.x & 7) * ((nwg) >> 3) + (blockIdx.x >> 3);

// ---------------------------------------------------------------------------
// GEMM-A: Q projection (400 blocks) + SR-conv split-K (448 blocks) merged.
// ---------------------------------------------------------------------------
__global__ __launch_bounds__(256) void k_gemmA(const f16* __restrict__ xT,
                                               const f16* __restrict__ WqT,
                                               f16* __restrict__ Qh,
                                               const f16* __restrict__ WsrP,
                                               float* __restrict__ XRp) {
  __shared__ GemmSmem sm;
  GEMM128_PRE();
  XCD_SWZ(848);
  int wg = bid;
  if (wg < 400) {             // ---- Q projection: b4 x m25 x n4 ----
    const int b = wg / 100, t = wg % 100;
    const int m0 = (t >> 2) * 128, n0 = (t & 3) * 128;
    const f16* xb = xT + (size_t)b * NTOK * CDIM;
    const int r0 = wv * 32 + lr, r1 = r0 + 16;
    const f16* a0 = xb + (size_t)min(m0 + r0, NTOK - 1) * CDIM + lc;
    const f16* a1 = xb + (size_t)min(m0 + r1, NTOK - 1) * CDIM + lc;
    const f16* b0 = WqT + (size_t)(n0 + r0) * CDIM + lc;
    const f16* b1 = WqT + (size_t)(n0 + r1) * CDIM + lc;
    gemm128(&sm, a0, a1, b0, b1, lane, wv, wm, wn, quad, tx, acc);
    f16* qhB = Qh + (size_t)b * NTOK * CDIM;
#pragma unroll
    for (int i = 0; i < 4; ++i)
#pragma unroll
      for (int rg = 0; rg < 4; ++rg) {
        const int m = m0 + wm * 64 + i * 16 + quad * 4 + rg;
        if (m >= NTOK) continue;
#pragma unroll
        for (int j = 0; j < 4; ++j)
          qhB[(size_t)m * CDIM + n0 + wn * 64 + j * 16 + tx] = (f16)acc[i][j][rg];
      }
  } else {                    // ---- SR conv split-K: (b,kc)16 x m7 x n4 ----
    wg -= 400;
    const int bkc = wg / 28, r = wg % 28;
    const int b = bkc >> 2, kc = bkc & 3;
    const int m0 = (r >> 2) * 128, n0 = (r & 3) * 128;
    const f16* xb = xT + (size_t)b * NTOK * CDIM;
    const int r0 = wv * 32 + lr, r1 = r0 + 16;
    int am0 = m0 + r0; if (am0 >= KNTOK) am0 = 0;
    int am1 = m0 + r1; if (am1 >= KNTOK) am1 = 0;
    const int sp0 = 112 * (am0 / KH) + 2 * (am0 % KH) + (kc >> 1) * FSP + (kc & 1);
    const int sp1 = 112 * (am1 / KH) + 2 * (am1 % KH) + (kc >> 1) * FSP + (kc & 1);
    const f16* a0 = xb + (size_t)sp0 * CDIM + lc;
    const f16* a1 = xb + (size_t)sp1 * CDIM + lc;
    const f16* b0 = WsrP + (size_t)(n0 + r0) * 2048 + kc * 512 + lc;
    const f16* b1 = WsrP + (size_t)(n0 + r1) * 2048 + kc * 512 + lc;
    gemm128(&sm, a0, a1, b0, b1, lane, wv, wm, wn, quad, tx, acc);
    float* dst = XRp + (size_t)(kc * BATCH + b) * KNTOK * CDIM;
#pragma unroll
    for (int i = 0; i < 4; ++i)
#pragma unroll
      for (int rg = 0; rg < 4; ++rg) {
        const int m = m0 + wm * 64 + i * 16 + quad * 4 + rg;
        if (m >= KNTOK) continue;
#pragma unroll
        for (int j = 0; j < 4; ++j)
          dst[(size_t)m * CDIM + n0 + wn * 64 + j * 16 + tx] = acc[i][j][rg];
      }
  }
}

// ---------------------------------------------------------------------------
// LN (R18): wave-per-row.  784 blocks x 4 waves; each wave owns one row, lane
// covers 8 channels.  No LDS, no __syncthreads — full 64-lane shfl reduce.
// ---------------------------------------------------------------------------
__global__ __launch_bounds__(256) void k_ln(const float* __restrict__ XRp,
                                            const float* __restrict__ b_sr,
                                            const float* __restrict__ gamma,
                                            const float* __restrict__ beta,
                                            f16* __restrict__ oh) {
  const int tid = threadIdx.x, wv = tid >> 6, lane = tid & 63;
  const int row = blockIdx.x * 4 + wv;
  const size_t slab = (size_t)BATCH * KNTOK * CDIM;
  const float* p = XRp + (size_t)row * CDIM + lane * 8;
  float v[8];
#pragma unroll
  for (int j = 0; j < 8; j += 4) {
    float4 a0 = *(const float4*)&p[j];
    float4 a1 = *(const float4*)&p[j + slab];
    float4 a2 = *(const float4*)&p[j + 2 * slab];
    float4 a3 = *(const float4*)&p[j + 3 * slab];
    float4 bs = *(const float4*)&b_sr[lane * 8 + j];
    v[j]     = a0.x + a1.x + a2.x + a3.x + bs.x;
    v[j + 1] = a0.y + a1.y + a2.y + a3.y + bs.y;
    v[j + 2] = a0.z + a1.z + a2.z + a3.z + bs.z;
    v[j + 3] = a0.w + a1.w + a2.w + a3.w + bs.w;
  }
  float s = 0.f, s2 = 0.f;
#pragma unroll
  for (int j = 0; j < 8; ++j) { s += v[j]; s2 += v[j] * v[j]; }
#pragma unroll
  for (int mask = 32; mask >= 1; mask >>= 1) {
    s  += __shfl_xor(s, mask, 64);
    s2 += __shfl_xor(s2, mask, 64);
  }
  const float mu  = s * (1.f / CDIM);
  const float var = s2 * (1.f / CDIM) - mu * mu;
  const float rs  = rsqrtf(var + 1e-5f);
  half8 o;
#pragma unroll
  for (int j = 0; j < 8; ++j)
    o[j] = (f16)((v[j] - mu) * rs * gamma[lane * 8 + j] + beta[lane * 8 + j]);
  *(half8*)&oh[(size_t)row * CDIM + lane * 8] = o;
}

// ---------------------------------------------------------------------------
// KV projection (224 blocks) + scatter.  K -> [b][h][m][d]; V -> [b][h][d][m].
// ---------------------------------------------------------------------------
__global__ __launch_bounds__(256) void k_kvproj(const f16* __restrict__ XRh,
                                                const f16* __restrict__ WkvT,
                                                f16* __restrict__ Kh,
                                                f16* __restrict__ Vt) {
  __shared__ GemmSmem sm;
  GEMM128_PRE();
  XCD_SWZ(224);
  const int b = bid / 56, r = bid % 56;
  const int m0 = (r / 8) * 128, n0 = (r % 8) * 128;
  const f16* ab = XRh + (size_t)b * KNTOK * CDIM;
  const int r0 = wv * 32 + lr, r1 = r0 + 16;
  const f16* a0 = ab + (size_t)min(m0 + r0, KNTOK - 1) * CDIM + lc;
  const f16* a1 = ab + (size_t)min(m0 + r1, KNTOK - 1) * CDIM + lc;
  const f16* b0 = WkvT + (size_t)(n0 + r0) * CDIM + lc;
  const f16* b1 = WkvT + (size_t)(n0 + r1) * CDIM + lc;
  gemm128(&sm, a0, a1, b0, b1, lane, wv, wm, wn, quad, tx, acc);
#pragma unroll
  for (int i = 0; i < 4; ++i)
#pragma unroll
    for (int rg = 0; rg < 4; ++rg) {
      const int m = m0 + wm * 64 + i * 16 + quad * 4 + rg;
      if (m >= KNTOK) continue;
#pragma unroll
      for (int j = 0; j < 4; ++j) {
        const int o2 = n0 + wn * 64 + j * 16 + tx;
        const int d = o2 >> 4, hh = (o2 >> 1) & 7;
        const float v = acc[i][j][rg];
        if (o2 & 1)
          Vt[((size_t)(b * NHEAD + hh) * HD + d) * KNTOK + m] = (f16)v;
        else
          Kh[((size_t)(b * NHEAD + hh) * KNTOK + m) * HD + d] = (f16)v;
      }
    }
}

// ---------------------------------------------------------------------------
// Attention (R23 = exact R21 / R18 structure, session best: setprio removed
// — clock-normalized it was neutral on attn and the total regressed).
// SWAPPED QK^T (S^T = mfma(K,Q)), packed-b32 P writes, aq fragments hoisted
// from LDS Qhs (the relay is load-bearing for the compiler's schedule —
// removing it regressed 3x in R9/R10/R19), K/V dbuf + 1 barrier per chunk,
// f16 natural-order bias.  LDS 73.7 KB -> 2 blocks/CU.
// ---------------------------------------------------------------------------
#define LSTR 72
__global__ __launch_bounds__(256) void k_attn(const f16* __restrict__ Qh,
                                              const f16* __restrict__ Kh,
                                              const f16* __restrict__ Vt,
                                              const f16* __restrict__ biasT,
                                              f16* __restrict__ Oh) {
  __shared__ f16 Qhs[128][LSTR];
  __shared__ f16 Khs[2][64][LSTR], Vts[2][64][LSTR];
  __shared__ f16 Ps[4][32][LSTR];
  const int b = blockIdx.x >> 3, h = blockIdx.x & 7;
  const int n0 = blockIdx.y * 128;
  const int tid = threadIdx.x, lane = tid & 63, wv = tid >> 6;
  const int quad = lane >> 4, tx = lane & 15;
  const int rr = tid >> 2, sg = (tid & 3) * 16;   // K/V staging coords
  const int qr = tid >> 1, qs = (tid & 1) * 32;   // Q staging coords

  const f16* khB = Kh + (size_t)(b * NHEAD + h) * KNTOK * HD;
  const f16* vtB = Vt + (size_t)(b * NHEAD + h) * HD * KNTOK;

  {  // stage Q (128 rows x 64, clamp tail rows) and chunk 0 of K/V -> buf 0
    const int qrow = min(n0 + qr, NTOK - 1);
    const f16* src = Qh + ((size_t)b * NTOK + qrow) * CDIM + h * HD + qs;
    *(half8*)&Qhs[qr][qs]      = *(const half8*)&src[0];
    *(half8*)&Qhs[qr][qs + 8]  = *(const half8*)&src[8];
    *(half8*)&Qhs[qr][qs + 16] = *(const half8*)&src[16];
    *(half8*)&Qhs[qr][qs + 24] = *(const half8*)&src[24];
    const size_t koff = (size_t)rr * HD + sg;
    *(half8*)&Khs[0][rr][sg]     = *(const half8*)&khB[koff];
    *(half8*)&Khs[0][rr][sg + 8] = *(const half8*)&khB[koff + 8];
    const size_t voff = (size_t)rr * KNTOK + sg;
    *(half8*)&Vts[0][rr][sg]     = *(const half8*)&vtB[voff];
    *(half8*)&Vts[0][rr][sg + 8] = *(const half8*)&vtB[voff + 8];
  }

  // bias base: row = q-row (i*16+tx), col base = quad*4 (k contiguous per rg)
  size_t bbase[2];
#pragma unroll
  for (int i = 0; i < 2; ++i) {
    const int grow = min(n0 + wv * 32 + i * 16 + tx, NTOK - 1);
    bbase[i] = (size_t)grow * BIAS_LD + quad * 4;
  }

  floatx4 acc_o[2][4];
#pragma unroll
  for (int i = 0; i < 2; ++i)
#pragma unroll
    for (int t = 0; t < 4; ++t) acc_o[i][t] = (floatx4){0.f, 0.f, 0.f, 0.f};
  float l_part[2] = {0.f, 0.f};
  __syncthreads();

  // hoisted Q fragments (loop-invariant): aq[i][ks]
  half8 aq[2][2];
#pragma unroll
  for (int i = 0; i < 2; ++i)
#pragma unroll
    for (int ks = 0; ks < 2; ++ks)
      aq[i][ks] = *(const half8*)&Qhs[wv * 32 + i * 16 + tx][ks * 32 + quad * 8];

  half8 nk0, nk1, nv0, nv1;
  for (int jc = 0; jc < 13; ++jc) {
    const int cur = jc & 1, nxt = cur ^ 1;
    if (jc < 12) {  // register prefetch of next K/V chunk
      const int mbn = (jc + 1) * 64;
      const int km = min(mbn + rr, KNTOK - 1);
      const size_t koff = (size_t)km * HD + sg;
      nk0 = *(const half8*)&khB[koff];
      nk1 = *(const half8*)&khB[koff + 8];
      const int vc = min(mbn + sg, KNTOK - 16);
      const size_t voff = (size_t)rr * KNTOK + vc;
      nv0 = *(const half8*)&vtB[voff];
      nv1 = *(const half8*)&vtB[voff + 8];
    }

    // ---- S^T = K Q^T : sc[i][t][rg] = S[k = t*16+quad*4+rg][q = i*16+tx] ----
    floatx4 sc[2][4];
#pragma unroll
    for (int i = 0; i < 2; ++i)
#pragma unroll
      for (int t = 0; t < 4; ++t) sc[i][t] = (floatx4){0.f, 0.f, 0.f, 0.f};
#pragma unroll
    for (int ks = 0; ks < 2; ++ks) {
      const int kk = ks * 32 + quad * 8;
#pragma unroll
      for (int t = 0; t < 4; ++t) {
        const half8 bk = *(const half8*)&Khs[cur][t * 16 + tx][kk];
#pragma unroll
        for (int i = 0; i < 2; ++i)
          sc[i][t] = __builtin_amdgcn_mfma_f32_16x16x32_f16(bk, aq[i][ks], sc[i][t], 0, 0, 0);
      }
    }

    // ---- softmax: P[q][k] with k-runs of 4 per lane -> packed b32 writes ----
#pragma unroll
    for (int i = 0; i < 2; ++i) {
      const int prow = i * 16 + tx;
#pragma unroll
      for (int t = 0; t < 4; ++t) {
        const half4 bb = *(const half4*)&biasT[bbase[i] + jc * 64 + t * 16];
        const float p0 = __expf(fmaf(sc[i][t][0], SCALE_ATT, (float)bb[0]));
        const float p1 = __expf(fmaf(sc[i][t][1], SCALE_ATT, (float)bb[1]));
        const float p2 = __expf(fmaf(sc[i][t][2], SCALE_ATT, (float)bb[2]));
        const float p3 = __expf(fmaf(sc[i][t][3], SCALE_ATT, (float)bb[3]));
        l_part[i] += (p0 + p1) + (p2 + p3);
        half2v h01 = {(f16)p0, (f16)p1};
        half2v h23 = {(f16)p2, (f16)p3};
        *(half2v*)&Ps[wv][prow][t * 16 + quad * 4]     = h01;
        *(half2v*)&Ps[wv][prow][t * 16 + quad * 4 + 2] = h23;
      }
    }

    // ---- O += P V ----
#pragma unroll
    for (int ks = 0; ks < 2; ++ks) {
      const int kk = ks * 32 + quad * 8;
      half8 ap[2];
#pragma unroll
      for (int i = 0; i < 2; ++i)
        ap[i] = *(const half8*)&Ps[wv][i * 16 + tx][kk];
#pragma unroll
      for (int t = 0; t < 4; ++t) {
        const half8 bv = *(const half8*)&Vts[cur][t * 16 + tx][kk];
#pragma unroll
        for (int i = 0; i < 2; ++i)
          acc_o[i][t] = __builtin_amdgcn_mfma_f32_16x16x32_f16(ap[i], bv, acc_o[i][t], 0, 0, 0);
      }
    }
    if (jc < 12) {  // write prefetched chunk into the other buffer (no hazard)
      *(half8*)&Khs[nxt][rr][sg]     = nk0;
      *(half8*)&Khs[nxt][rr][sg + 8] = nk1;
      *(half8*)&Vts[nxt][rr][sg]     = nv0;
      *(half8*)&Vts[nxt][rr][sg + 8] = nv1;
    }
    __syncthreads();   // single barrier: next-buf writes visible, cur reads done
  }

  // ---- epilogue: row-sum lives per (i, tx); reduce over quads, then
  //      redistribute to the acc layout (row = i*16 + quad*4 + rg). ----
#pragma unroll
  for (int i = 0; i < 2; ++i) {
    float l = l_part[i];
    l += __shfl_xor(l, 16, 64);
    l += __shfl_xor(l, 32, 64);   // all lanes now hold sum for row i*16+tx
#pragma unroll
    for (int rg = 0; rg < 4; ++rg) {
      const float inv = 1.f / __shfl(l, quad * 4 + rg, 64);
      const int grow = n0 + wv * 32 + i * 16 + quad * 4 + rg;
      if (grow < NTOK) {
        const size_t base = ((size_t)b * NTOK + grow) * CDIM + h * HD;
#pragma unroll
        for (int t = 0; t < 4; ++t)
          Oh[base + t * 16 + tx] = (f16)(acc_o[i][t][rg] * inv);
      }
    }
  }
}

// ---------------------------------------------------------------------------
// Output projection (400 blocks, 128x128) + bp, fp32 transposed (b, co, n).
// ---------------------------------------------------------------------------
__global__ __launch_bounds__(256) void k_outproj(const f16* __restrict__ Og,
                                                 const f16* __restrict__ WpT,
                                                 const float* __restrict__ bp,
                                                 float* __restrict__ out) {
  __shared__ GemmSmem sm;
  GEMM128_PRE();
  XCD_SWZ(400);
  const int b = bid / 100, t = bid % 100;
  const int m0 = (t >> 2) * 128, n0 = (t & 3) * 128;
  const f16* ab = Og + (size_t)b * NTOK * CDIM;
  const int r0 = wv * 32 + lr, r1 = r0 + 16;
  const f16* a0 = ab + (size_t)min(m0 + r0, NTOK - 1) * CDIM + lc;
  const f16* a1 = ab + (size_t)min(m0 + r1, NTOK - 1) * CDIM + lc;
  const f16* b0 = WpT + (size_t)(n0 + r0) * CDIM + lc;
  const f16* b1 = WpT + (size_t)(n0 + r1) * CDIM + lc;
  gemm128(&sm, a0, a1, b0, b1, lane, wv, wm, wn, quad, tx, acc);
#pragma unroll
  for (int j = 0; j < 4; ++j) {
    const int co = n0 + wn * 64 + j * 16 + tx;
    const float bpv = bp[co];
    float* obase = out + ((size_t)b * CDIM + co) * NTOK;
#pragma unroll
    for (int i = 0; i < 4; ++i) {
      const int mb4 = m0 + wm * 64 + i * 16 + quad * 4;
      if (mb4 < NTOK) {
        floatx4 v = acc[i][j] + bpv;
        *(floatx4*)&obase[mb4] = v;
      }
    }
  }
}

// ---------------------------------------------------------------------------
extern "C" void kernel_launch(void* const* d_in, const int* in_sizes, int n_in,
                              void* d_out, int out_size, void* d_ws, size_t ws_size,
                              hipStream_t stream) {
  const float* x     = (const float*)d_in[0];
  const float* Wq    = (const float*)d_in[1];
  const float* Wkv   = (const float*)d_in[2];
  const float* Wsr   = (const float*)d_in[3];
  const float* b_sr  = (const float*)d_in[4];
  const float* gamma = (const float*)d_in[5];
  const float* beta  = (const float*)d_in[6];
  const float* Wp    = (const float*)d_in[7];
  const float* bp    = (const float*)d_in[8];
  const float* pos   = (const float*)d_in[9];
  float* out = (float*)d_out;

  char* p = (char*)d_ws;
  auto alloc = [&](size_t bytes) -> void* {
    void* r = (void*)p;
    p += (bytes + 255) & ~(size_t)255;
    return r;
  };
  const size_t SZ_BNC = (size_t)BATCH * NTOK * CDIM;
  const size_t SZ_BKC = (size_t)BATCH * KNTOK * CDIM;
  const size_t SZ_KV  = (size_t)BATCH * NHEAD * KNTOK * HD;

  f16* xT    = (f16*)alloc(SZ_BNC * 2);          // aliased later as Og
  f16* WqT   = (f16*)alloc(512 * 512 * 2);
  f16* WkvT  = (f16*)alloc(1024 * 512 * 2);
  f16* WpT   = (f16*)alloc(512 * 512 * 2);
  f16* WsrP  = (f16*)alloc(512 * 2048 * 2);
  f16* Qh    = (f16*)alloc(SZ_BNC * 2);
  float* XRp = (float*)alloc(SZ_BKC * 4 * 4);    // 4 split-K partials; aliased: Kh
  f16* XRh   = (f16*)alloc(SZ_BKC * 2);
  f16* Vt    = (f16*)alloc(SZ_KV * 2);
  f16* biasT = (f16*)alloc((size_t)NTOK * BIAS_LD * 2);   // f16 table, natural order

  f16* Kh = (f16*)XRp;  // XRp dead after k_ln; Kh written by k_kvproj
  f16* Og = xT;         // xT dead after k_gemmA

  const dim3 blk(256);
  k_prep   <<<dim3(5472), blk, 0, stream>>>(x, Wq, Wkv, Wp, Wsr, pos,
                                            xT, WqT, WkvT, WpT, WsrP, biasT);
  k_gemmA  <<<dim3(848),  blk, 0, stream>>>(xT, WqT, Qh, WsrP, XRp);
  k_ln     <<<dim3(BATCH * KNTOK / 4), blk, 0, stream>>>(XRp, b_sr, gamma, beta, XRh);
  k_kvproj <<<dim3(224),  blk, 0, stream>>>(XRh, WkvT, Kh, Vt);
  k_attn   <<<dim3(BATCH * NHEAD, 25), blk, 0, stream>>>(Qh, Kh, Vt, biasT, Og);
  k_outproj<<<dim3(400),  blk, 0, stream>>>(Og, WpT, bp, out);
}